// Round 4
// baseline (15.639 us; speedup 1.0000x reference)
//
#include <hip/hip_runtime.h>
#include <cmath>

#define BB 64
#define TT 2048
#define DD 512
#define EE 1024
#define HH 102
#define PF 32                // prefetch rows; window (<=29 rows) provably inside
#define COEF 0.3989422917366028f

__device__ __forceinline__ float sigmoidf_(float x) { return 1.0f / (1.0f + expf(-x)); }

// One fused kernel, one block per batch, 1024 threads.
// Window prefetch (depends only on mu_tm1) overlaps the MLP:
//   mu = mu_tm1 + sigmoid(.) in (mu_tm1, mu_tm1+1); sig > 0.5 => halfwidth <= 14
//   => window subset of [floor(mu_tm1)-14, floor(mu_tm1)+15] (30 rows <= PF=32).
__global__ __launch_bounds__(1024) void k_fused(const float* __restrict__ query,
                                                const float* __restrict__ x,
                                                const float* __restrict__ mu_tm1,
                                                const float* __restrict__ W1,
                                                const float* __restrict__ b1,
                                                const float* __restrict__ W2,
                                                const float* __restrict__ b2,
                                                float* __restrict__ out) {
    __shared__ float4 xw4[PF * (DD / 4)];     // 64 KB prefetched window
    __shared__ float  qs[EE];                 // 4 KB
    __shared__ float  hidp[16][HH];           // partial hidden sums
    __shared__ float  hid[HH];
    __shared__ float  al[32];                 // [0]=j0, [1]=n, [2..30]=alpha
    const float* xw = (const float*)xw4;

    const int b   = blockIdx.x;
    const int tid = threadIdx.x;

    // ---- issue early loads: mu_tm1 (drives prefetch base) + query row ----
    const float mut = mu_tm1[b];                               // uniform
    if (tid < EE / 4) ((float4*)qs)[tid] = ((const float4*)(query + (size_t)b * EE))[tid];

    const int pbase = min(max((int)floorf(mut) - 14, 0), TT - PF);

    // ---- issue window prefetch into registers (flies during the MLP) ----
    float4 pf0, pf1, pf2, pf3;
    {
        const float4* xb4 = (const float4*)(x + ((size_t)b * TT + (size_t)pbase) * DD);
        pf0 = xb4[tid];
        pf1 = xb4[tid + 1024];
        pf2 = xb4[tid + 2048];
        pf3 = xb4[tid + 3072];
    }
    __syncthreads();   // qs visible

    // ---- layer 1: 16 e-slices x 51 hidden-pairs ----
    {
        const int sl = tid >> 6;          // e-slice 0..15 (64 e each)
        const int hp = tid & 63;          // hidden pair, active < 51
        if (hp < 51) {
            const float* qp = qs + sl * 64;
            const float* wbase = W1 + (size_t)sl * 64 * HH + 2 * hp;
            float a0 = 0.f, a1 = 0.f, a2 = 0.f, a3 = 0.f;
            #pragma unroll 8
            for (int e = 0; e < 64; e += 2) {
                const float2 w0 = *(const float2*)(wbase + (size_t)e * HH);
                const float2 w1 = *(const float2*)(wbase + (size_t)(e + 1) * HH);
                a0 = fmaf(qp[e],     w0.x, a0);
                a1 = fmaf(qp[e],     w0.y, a1);
                a2 = fmaf(qp[e + 1], w1.x, a2);
                a3 = fmaf(qp[e + 1], w1.y, a3);
            }
            hidp[sl][2 * hp]     = a0 + a2;
            hidp[sl][2 * hp + 1] = a1 + a3;
        }
    }

    // ---- land the prefetch in LDS (loads have had the whole MLP to finish) ----
    xw4[tid]        = pf0;
    xw4[tid + 1024] = pf1;
    xw4[tid + 2048] = pf2;
    xw4[tid + 3072] = pf3;
    __syncthreads();

    if (tid < HH) {
        float s = b1[tid];
        #pragma unroll
        for (int sl = 0; sl < 16; ++sl) s += hidp[sl][tid];
        hid[tid] = fmaxf(s, 0.f);
    }
    __syncthreads();

    // ---- layer 2 + window + alpha (wave 0) ----
    if (tid < 64) {
        float p0 = 0.f, p1 = 0.f;
        for (int h = tid; h < HH; h += 64) {
            const float hv = hid[h];
            p0 = fmaf(hv, W2[2 * h + 0], p0);
            p1 = fmaf(hv, W2[2 * h + 1], p1);
        }
        for (int m = 32; m >= 1; m >>= 1) {
            p0 += __shfl_xor(p0, m, 64);
            p1 += __shfl_xor(p1, m, 64);
        }
        const float sig = sigmoidf_(p0 + b2[0]) * 0.5f + 0.5f;   // (0.5, 1]
        const float mu  = mut + sigmoidf_(p1 + b2[1]);

        const float w = ceilf(sqrtf(90.0f / sig));               // <= 14
        int j0 = max(0, (int)ceilf(mu - w));
        j0 = min(j0, TT - 1);
        const int j1 = min(TT - 1, (int)floorf(mu + w));
        const int n  = max(1, min(j1 - j0 + 1, 29));

        float ph = 0.f;
        if (tid < n) {
            const float dd = mu - (float)(j0 + tid);
            ph = expf(-0.5f * sig * dd * dd);
        }
        float sp = ph;
        for (int m = 32; m >= 1; m >>= 1) sp += __shfl_xor(sp, m, 64);
        const float Z = COEF * sp + (float)TT * 1e-8f;           // exact 1e-8 tail

        if (tid == 0) { al[0] = (float)(j0 - pbase); al[1] = (float)n; }
        if (tid < 29) al[2 + tid] = (tid < n) ? (COEF * ph + 1e-8f) / Z : 0.f;
    }
    __syncthreads();

    // ---- ctx reduce from prefetched LDS window ----
    const int r0 = (int)al[0];           // window start within prefetch
    const int n  = (int)al[1];
    if (tid < DD) {
        float acc = 0.f;
        for (int k = 0; k < n; ++k)
            acc = fmaf(al[2 + k], xw[(r0 + k) * DD + tid], acc);
        out[(size_t)b * DD + tid] = acc;
    }
}

extern "C" void kernel_launch(void* const* d_in, const int* in_sizes, int n_in,
                              void* d_out, int out_size, void* d_ws, size_t ws_size,
                              hipStream_t stream) {
    const float* query  = (const float*)d_in[0];
    const float* x      = (const float*)d_in[1];
    const float* mu_tm1 = (const float*)d_in[2];
    const float* W1     = (const float*)d_in[3];
    const float* b1     = (const float*)d_in[4];
    const float* W2     = (const float*)d_in[5];
    const float* b2     = (const float*)d_in[6];
    float* out = (float*)d_out;

    hipLaunchKernelGGL(k_fused, dim3(BB), dim3(1024), 0, stream,
                       query, x, mu_tm1, W1, b1, W2, b2, out);
}